// Round 1
// baseline (1685.392 us; speedup 1.0000x reference)
//
#include <hip/hip_runtime.h>

#define NTIPS 512
#define DIM   510                     // internal nodes = ntips - 2
#define TOTAL 1022
#define BS    64
#define ITERS 50
#define SLABF 16                      // features per workgroup slab
#define NSLAB 32
#define NWG   (BS * NSLAB)            // 2048 workgroups
#define NPART ((size_t)ITERS * BS * NSLAB)

#define ROWEL 16                      // u16 elems per row-slab (32 B)
#define XSEC   (DIM * ROWEL)          // evolving X section
#define ONEOFF XSEC                   // 16 one-hot const rows
#define ZROW   (XSEC + 16 * ROWEL)    // all-zero const row
#define BSTRIDE (XSEC + 17 * ROWEL)   // u16 per LDS buffer
#define BUFB   (BSTRIDE * 2)          // bytes per LDS buffer = 16864

#define XB ((size_t)BS * DIM * NTIPS) // u16 elems per snapshot slot

typedef unsigned short u16;
typedef unsigned int   u32;
typedef float f32x2 __attribute__((ext_vector_type(2)));

// bf16 RNE helpers — bit-identical to validated arithmetic
__device__ __forceinline__ u16 f2bf(float x) {
    u32 u = __float_as_uint(x);
    return (u16)((u + 0x7FFFu + ((u >> 16) & 1u)) >> 16);
}
__device__ __forceinline__ float bf2f(u16 h) { return __uint_as_float(((u32)h) << 16); }
__device__ __forceinline__ float bflo(u32 p) { return __uint_as_float(p << 16); }
__device__ __forceinline__ float bfhi(u32 p) { return __uint_as_float(p & 0xFFFF0000u); }
__device__ __forceinline__ f32x2 unpk(u32 p) {
    f32x2 r; r.x = bflo(p); r.y = bfhi(p); return r;   // (lo elem, hi elem)
}

#if defined(__has_builtin)
#  if __has_builtin(__builtin_amdgcn_cvt_pk_bf16_f32)
#    define HAVE_PKBF 1
#  endif
#endif
#ifdef HAVE_PKBF
typedef __bf16 bf16x2 __attribute__((ext_vector_type(2)));
__device__ __forceinline__ u32 pkbf(float a, float b) {   // lo=a, hi=b, RNE
    bf16x2 r = __builtin_amdgcn_cvt_pk_bf16_f32(a, b);
    return __builtin_bit_cast(u32, r);
}
#else
__device__ __forceinline__ u32 pkbf(float a, float b) {
    return (u32)f2bf(a) | ((u32)f2bf(b) << 16);
}
#endif

// exact f32 RN division by 3 (correctly rounded via double) — validated chain
__device__ __forceinline__ float div3(float x) {
    return (float)((double)x * (1.0 / 3.0));
}

// register-resident gather offsets (BYTE units, buffer-relative)
__device__ __forceinline__ void make_offsets(const int* __restrict__ edge,
        int b, int sl, int rg, int lbyte, int nr, u32 offB[8][3]) {
    #pragma unroll
    for (int k = 0; k < 8; ++k) if (k < nr) {
        const int i = rg + 64 * k;
        const int* ep = edge + ((size_t)b * TOTAL + NTIPS + i) * 3;
        #pragma unroll
        for (int t = 0; t < 3; ++t) {
            const int e = ep[t];
            u32 off;
            if (e >= NTIPS)          off = (u32)((e - NTIPS) * ROWEL);
            else if ((e >> 4) == sl) off = (u32)(ONEOFF + (e & 15) * ROWEL);
            else                     off = (u32)ZROW;
            offB[k][t] = off * 2u + (u32)lbyte;
        }
    }
}

__device__ __forceinline__ void init_const_rows(u16* X, int tid) {
    for (int j = tid; j < 17 * ROWEL; j += 256) {
        const int row = j >> 4, col = j & 15;
        const u16 v = (row == col) ? (u16)0x3F80 : (u16)0;  // row 16 = zeros
        X[ONEOFF + j] = v;
        X[BSTRIDE + ONEOFF + j] = v;
    }
}

// ---------------------------------------------------------------------------
// chunk q: W steps (sBeg..sBeg+W-1), sBeg ≡ 1 (mod 4) always.
// Loads X_{sBeg-1} from slot 0 (all chunk boundaries are multiples of 4).
// Snapshots EVERY step s into slot s&3 = (u+1)&3 (compile-time).
// Fused findS: last WG to finish (device-scope atomic counter) scans partials.
// Arithmetic is bit-identical to the validated chain (f32x2 pk ops are
// IEEE-identical per lane; delta/reduction order preserved exactly).
// ---------------------------------------------------------------------------
template<int W>
__global__ __launch_bounds__(256, 4) void chunk_kernel(
        const int* __restrict__ edge, float* __restrict__ partials,
        int* __restrict__ ctrl, u16* __restrict__ slots, int q, int sBeg) {
    if (q >= 2 && ctrl[2] != 0) return;          // converged: skip

    __shared__ u16 X[2 * BSTRIDE];
    __shared__ float redL[2][4];
    __shared__ int lastFlag;

    const int wg = blockIdx.x, b = wg >> 5, sl = wg & 31;
    const int tid = threadIdx.x, rg = tid >> 2;
    const int lbyte = (tid & 3) << 3;            // byte offset in row (8 B)
    const int nr = (rg < 62) ? 8 : 7;
    char* Xc = reinterpret_cast<char*>(X);
    const u32 r0b = (u32)(rg * 32 + lbyte);      // own-row LDS byte base

    u32 offB[8][3];
    make_offsets(edge, b, sl, rg, lbyte, nr, offB);

    // global byte offsets of own rows within one snapshot slot
    u32 rowByte[8];
    #pragma unroll
    for (int k = 0; k < 8; ++k)
        rowByte[k] = (u32)(((size_t)b * DIM + (size_t)(rg + 64 * k)) * NTIPS * 2
                           + (size_t)sl * SLABF * 2) + (u32)lbyte;

    if (q == 1) {
        for (int j = tid; j < XSEC / 2; j += 256)
            reinterpret_cast<u32*>(X)[j] = 0x3B003B00u;   // X0 = bf16(1/512)
    } else {
        const char* src0 = reinterpret_cast<const char*>(slots);  // slot 0
        #pragma unroll
        for (int k = 0; k < 8; ++k) if (k < nr)
            *reinterpret_cast<uint2*>(Xc + r0b + (k << 11)) =
                *reinterpret_cast<const uint2*>(src0 + rowByte[k]);
    }
    init_const_rows(X, tid);

    // old-row values in registers (own rows, written by self — no barrier)
    f32x2 old01[8], old23[8];
    #pragma unroll
    for (int k = 0; k < 8; ++k) if (k < nr) {
        const uint2 ov = *reinterpret_cast<const uint2*>(Xc + r0b + (k << 11));
        old01[k] = unpk(ov.x); old23[k] = unpk(ov.y);
    }
    __syncthreads();

    #pragma unroll
    for (int u = 0; u < W; ++u) {
        const int s = sBeg + u;                  // runtime (partials index only)
        const int srcB = (u & 1) ? BUFB : 0;     // compile-time after unroll
        const int dstB = ((u + 1) & 1) ? BUFB : 0;
        const int slotIdx = (u + 1) & 3;         // s ≡ 1+u (mod 4) by design
        char* slotC = reinterpret_cast<char*>(slots) + (size_t)slotIdx * (XB * 2);
        float dacc = 0.f;
        #pragma unroll
        for (int k = 0; k < 8; ++k) if (k < nr) {
            const uint2 g0 = *reinterpret_cast<const uint2*>(Xc + offB[k][0] + srcB);
            const uint2 g1 = *reinterpret_cast<const uint2*>(Xc + offB[k][1] + srcB);
            const uint2 g2 = *reinterpret_cast<const uint2*>(Xc + offB[k][2] + srcB);
            const f32x2 a01 = (unpk(g0.x) + unpk(g1.x)) + unpk(g2.x);
            const f32x2 a23 = (unpk(g0.y) + unpk(g1.y)) + unpk(g2.y);
            uint2 nv;
            nv.x = pkbf(div3(a01.x), div3(a01.y));
            nv.y = pkbf(div3(a23.x), div3(a23.y));
            *reinterpret_cast<uint2*>(Xc + r0b + ((k << 11) + dstB)) = nv;
            *reinterpret_cast<uint2*>(slotC + rowByte[k]) = nv;   // snapshot
            const f32x2 n01 = unpk(nv.x), n23 = unpk(nv.y);
            const f32x2 d01v = n01 - old01[k];
            const f32x2 d23v = n23 - old23[k];
            const u32 d01 = pkbf(d01v.x, d01v.y);
            const u32 d23 = pkbf(d23v.x, d23v.y);
            dacc += fabsf(bflo(d01));
            dacc += fabsf(bfhi(d01));
            dacc += fabsf(bflo(d23));
            dacc += fabsf(bfhi(d23));
            old01[k] = n01; old23[k] = n23;
        }
        #pragma unroll
        for (int off = 32; off > 0; off >>= 1) dacc += __shfl_down(dacc, off);
        if ((tid & 63) == 0) redL[u & 1][tid >> 6] = dacc;
        __syncthreads();
        if (tid == 0) {
            const float dtot = ((redL[u & 1][0] + redL[u & 1][1])
                                + redL[u & 1][2]) + redL[u & 1][3];
            partials[((size_t)(s - 1) * BS + b) * NSLAB + sl] = dtot;
        }
    }

    // ---- fused findS: last workgroup to arrive scans partials --------------
    __threadfence();                              // release partials writes
    if (tid == 0) {
        const int old = atomicAdd(&ctrl[3], 1);   // device-scope
        lastFlag = (old == (int)gridDim.x - 1);
    }
    __syncthreads();
    if (!lastFlag) return;
    if (tid == 0) ctrl[3] = 0;                    // reset for next chunk
    if (tid < 64) {
        __threadfence();                          // acquire partials
        const int smax = sBeg + W - 1;
        const float tol_bf = bf2f(f2bf(1e-5f));
        int S = -1;
        for (int s = 1; s <= smax; ++s) {
            const float* p = partials + ((size_t)(s - 1) * BS + tid) * NSLAB;
            float t = 0.f;
            #pragma unroll
            for (int kk = 0; kk < NSLAB; ++kk) t += p[kk];
            const float lnorm = bf2f(f2bf(t / 261120.0f));
            if (__ballot(lnorm > tol_bf) == 0ULL) { S = s; break; }
        }
        if (S < 0 && smax == ITERS) S = ITERS;    // cap at MAX_ITERS
        if (tid == 0 && S > 0) { ctrl[0] = S; ctrl[2] = 1; }
    }
}

// ---------------------------------------------------------------------------
// copyFinal: X_S (slot S&3 in d_out) -> finalX in ws. Pure BW copy (~12 µs).
// Needed because convert writes f32 over the whole d_out (would race slots).
// ---------------------------------------------------------------------------
__global__ __launch_bounds__(256) void copyfinal_kernel(
        const int* __restrict__ ctrl, const u16* __restrict__ slots,
        u16* __restrict__ finalX) {
    const int S = ctrl[0];
    const uint4* src = reinterpret_cast<const uint4*>(slots + (size_t)(S & 3) * XB);
    uint4* dst = reinterpret_cast<uint4*>(finalX);
    const size_t n = XB / 8;                      // uint4 = 8 u16
    for (size_t i = (size_t)blockIdx.x * 256 + threadIdx.x; i < n;
         i += (size_t)gridDim.x * 256)
        dst[i] = src[i];
}

// ---------------------------------------------------------------------------
// convert: d_out fp32 = [identity ; f32(bf16 finalX)] per batch.
// ---------------------------------------------------------------------------
__global__ __launch_bounds__(64) void convert_kernel(
        const u16* __restrict__ finalX, float* __restrict__ out) {
    const int r = blockIdx.x;                    // 0..1021
    const int b = blockIdx.y;
    const int f0 = threadIdx.x << 3;             // 8 floats per thread
    float4 lo, hi;
    if (r < NTIPS) {
        lo.x = (r == f0 + 0) ? 1.f : 0.f;
        lo.y = (r == f0 + 1) ? 1.f : 0.f;
        lo.z = (r == f0 + 2) ? 1.f : 0.f;
        lo.w = (r == f0 + 3) ? 1.f : 0.f;
        hi.x = (r == f0 + 4) ? 1.f : 0.f;
        hi.y = (r == f0 + 5) ? 1.f : 0.f;
        hi.z = (r == f0 + 6) ? 1.f : 0.f;
        hi.w = (r == f0 + 7) ? 1.f : 0.f;
    } else {
        const u16* row = finalX + ((size_t)b * DIM + (r - NTIPS)) * NTIPS + f0;
        const ushort4 a = *reinterpret_cast<const ushort4*>(row);
        const ushort4 c = *reinterpret_cast<const ushort4*>(row + 4);
        lo.x = bf2f(a.x); lo.y = bf2f(a.y); lo.z = bf2f(a.z); lo.w = bf2f(a.w);
        hi.x = bf2f(c.x); hi.y = bf2f(c.y); hi.z = bf2f(c.z); hi.w = bf2f(c.w);
    }
    float* drow = out + ((size_t)b * TOTAL + r) * NTIPS + f0;
    *reinterpret_cast<float4*>(drow)     = lo;
    *reinterpret_cast<float4*>(drow + 4) = hi;
}

extern "C" void kernel_launch(void* const* d_in, const int* in_sizes, int n_in,
                              void* d_out, int out_size, void* d_ws, size_t ws_size,
                              hipStream_t stream) {
    const int* edge = (const int*)d_in[1];       // (BS, TOTAL, 3) int32
    float* out = (float*)d_out;

    u16*   finalX = (u16*)d_ws;                  // XB u16 = 33.4 MB
    float* partials = (float*)((char*)d_ws + XB * sizeof(u16));
    int*   ctrl = (int*)(partials + NPART);      // [S, unused, found, wgCounter]

    // 4 rotating bf16 snapshot slots in d_out (4*XB*2 = 133.7 MB <= out_size)
    u16* slots = (u16*)d_out;

    hipMemsetAsync(ctrl, 0, 4 * sizeof(int), stream);

    // 12 chunks of width 4 + final chunk of width 2 (steps 49..50).
    // sBeg = 4q-3 ≡ 1 (mod 4) for every chunk — slot math relies on this.
    for (int q = 1; q <= 12; ++q)
        chunk_kernel<4><<<NWG, 256, 0, stream>>>(edge, partials, ctrl,
                                                 slots, q, 4 * q - 3);
    chunk_kernel<2><<<NWG, 256, 0, stream>>>(edge, partials, ctrl,
                                             slots, 13, 49);

    copyfinal_kernel<<<2048, 256, 0, stream>>>(ctrl, slots, finalX);
    convert_kernel<<<dim3(TOTAL, BS), 64, 0, stream>>>(finalX, out);
}

// Round 2
// 1190.678 us; speedup vs baseline: 1.4155x; 1.4155x over previous
//
#include <hip/hip_runtime.h>

#define NTIPS 512
#define DIM   510                     // internal nodes = ntips - 2
#define TOTAL 1022
#define BS    64
#define ITERS 50
#define SLABF 16                      // features per workgroup slab
#define NSLAB 32
#define NWG   (BS * NSLAB)            // 2048 workgroups
#define NPART ((size_t)ITERS * BS * NSLAB)

#define ROWEL 16                      // u16 elems per row-slab (32 B)
#define XSEC   (DIM * ROWEL)          // evolving X section
#define ONEOFF XSEC                   // 16 one-hot const rows
#define ZROW   (XSEC + 16 * ROWEL)    // all-zero const row
#define BSTRIDE (XSEC + 17 * ROWEL)   // u16 per LDS buffer
#define BUFB   (BSTRIDE * 2)          // bytes per LDS buffer = 16864

#define XB ((size_t)BS * DIM * NTIPS) // u16 elems per snapshot slot
#define SLOTB (XB * 2)                // bytes per snapshot slot (33.4 MB)
#define WGB  (DIM * ROWEL * 2)        // bytes per WG region in a slot = 16320

typedef unsigned short u16;
typedef unsigned int   u32;
typedef float f32x2 __attribute__((ext_vector_type(2)));

// bf16 RNE helpers
__device__ __forceinline__ u16 f2bf(float x) {
    u32 u = __float_as_uint(x);
    return (u16)((u + 0x7FFFu + ((u >> 16) & 1u)) >> 16);
}
__device__ __forceinline__ float bf2f(u16 h) { return __uint_as_float(((u32)h) << 16); }
__device__ __forceinline__ float bflo(u32 p) { return __uint_as_float(p << 16); }
__device__ __forceinline__ float bfhi(u32 p) { return __uint_as_float(p & 0xFFFF0000u); }
__device__ __forceinline__ f32x2 unpk(u32 p) {
    f32x2 r; r.x = bflo(p); r.y = bfhi(p); return r;   // (lo elem, hi elem)
}

#if defined(__has_builtin)
#  if __has_builtin(__builtin_amdgcn_cvt_pk_bf16_f32)
#    define HAVE_PKBF 1
#  endif
#endif
#ifdef HAVE_PKBF
typedef __bf16 bf16x2 __attribute__((ext_vector_type(2)));
__device__ __forceinline__ u32 pkbf(float a, float b) {   // lo=a, hi=b, RNE
    bf16x2 r = __builtin_amdgcn_cvt_pk_bf16_f32(a, b);
    return __builtin_bit_cast(u32, r);
}
#else
__device__ __forceinline__ u32 pkbf(float a, float b) {
    return (u32)f2bf(a) | ((u32)f2bf(b) << 16);
}
#endif

// correctly-rounded f32 division by 3 (Markstein mul+2fma; b=3 mantissa not
// all-ones -> final fma yields RN(x/3); bit-equivalent to the f64 path)
__device__ __forceinline__ f32x2 div3v(f32x2 x) {
    const float C = 0x1.555556p-2f;               // RN(1/3)
    f32x2 q0, r, q;
    q0.x = x.x * C;             q0.y = x.y * C;
    r.x = fmaf(-3.f, q0.x, x.x); r.y = fmaf(-3.f, q0.y, x.y);
    q.x = fmaf(r.x, C, q0.x);    q.y = fmaf(r.y, C, q0.y);
    return q;
}

// LDS-only barrier: waits LDS ops, does NOT drain vmcnt (snapshot stores
// stay in flight across steps). m201/HK pattern + rule-#18 sched guards.
__device__ __forceinline__ void barrier_lds_only() {
    __builtin_amdgcn_sched_barrier(0);
    asm volatile("s_waitcnt lgkmcnt(0)" ::: "memory");
    __builtin_amdgcn_s_barrier();
    __builtin_amdgcn_sched_barrier(0);
}

// register-resident gather offsets (BYTE units, LDS-buffer-relative)
__device__ __forceinline__ void make_offsets(const int* __restrict__ edge,
        int b, int sl, int rg, int lbyte, int nr, u32 offB[8][3]) {
    #pragma unroll
    for (int k = 0; k < 8; ++k) if (k < nr) {
        const int i = rg + 64 * k;
        const int* ep = edge + ((size_t)b * TOTAL + NTIPS + i) * 3;
        #pragma unroll
        for (int t = 0; t < 3; ++t) {
            const int e = ep[t];
            u32 off;
            if (e >= NTIPS)          off = (u32)((e - NTIPS) * ROWEL);
            else if ((e >> 4) == sl) off = (u32)(ONEOFF + (e & 15) * ROWEL);
            else                     off = (u32)ZROW;
            offB[k][t] = off * 2u + (u32)lbyte;
        }
    }
}

__device__ __forceinline__ void init_const_rows(u16* X, int tid) {
    for (int j = tid; j < 17 * ROWEL; j += 256) {
        const int row = j >> 4, col = j & 15;
        const u16 v = (row == col) ? (u16)0x3F80 : (u16)0;  // row 16 = zeros
        X[ONEOFF + j] = v;
        X[BSTRIDE + ONEOFF + j] = v;
    }
}

// ---------------------------------------------------------------------------
// chunk q: W steps (sBeg..sBeg+W-1). Snapshots EVERY step s into slot s&3
// using a SLAB-MAJOR layout: slot[wg][row][16] -> a wave stores contiguous
// 512-B segments (coalesced; R1's 1-KB-stride 32-B pattern was the 549 µs
// regression). Reload reads slot (sBeg-1)&3 coalesced. W<=4 guarantees no
// slot reuse within a chunk. Fused findS via last-WG atomic.
// ---------------------------------------------------------------------------
template<int W>
__global__ __launch_bounds__(256, 4) void chunk_kernel(
        const int* __restrict__ edge, float* __restrict__ partials,
        int* __restrict__ ctrl, u16* __restrict__ slots, int q, int sBeg) {
    if (q >= 2 && ctrl[2] != 0) return;          // converged: skip

    __shared__ u16 X[2 * BSTRIDE];
    __shared__ float redL[2][4];
    __shared__ int lastFlag;

    const int wg = blockIdx.x, b = wg >> 5, sl = wg & 31;
    const int tid = threadIdx.x, rg = tid >> 2;
    const int lbyte = (tid & 3) << 3;            // byte offset in row (8 B)
    const int nr = (rg < 62) ? 8 : 7;
    char* Xc = reinterpret_cast<char*>(X);
    const u32 r0b = (u32)(rg * 32 + lbyte);      // own-row LDS byte base

    u32 offB[8][3];
    make_offsets(edge, b, sl, rg, lbyte, nr, offB);

    // slab-major global byte offsets of own rows within one snapshot slot
    u32 rowByte[8];
    #pragma unroll
    for (int k = 0; k < 8; ++k)
        rowByte[k] = (u32)wg * (u32)WGB + (u32)((rg + 64 * k) * 32) + (u32)lbyte;

    if (q == 1) {
        for (int j = tid; j < XSEC / 2; j += 256)
            reinterpret_cast<u32*>(X)[j] = 0x3B003B00u;   // X0 = bf16(1/512)
    } else {
        const char* src0 = reinterpret_cast<const char*>(slots)
                         + (size_t)((sBeg - 1) & 3) * SLOTB;
        #pragma unroll
        for (int k = 0; k < 8; ++k) if (k < nr)
            *reinterpret_cast<uint2*>(Xc + r0b + (k << 11)) =
                *reinterpret_cast<const uint2*>(src0 + rowByte[k]);
    }
    init_const_rows(X, tid);

    // old-row values in registers (own rows, written by self — no barrier)
    f32x2 old01[8], old23[8];
    #pragma unroll
    for (int k = 0; k < 8; ++k) if (k < nr) {
        const uint2 ov = *reinterpret_cast<const uint2*>(Xc + r0b + (k << 11));
        old01[k] = unpk(ov.x); old23[k] = unpk(ov.y);
    }
    __syncthreads();

    #pragma unroll
    for (int u = 0; u < W; ++u) {
        const int s = sBeg + u;
        const int srcB = (u & 1) ? BUFB : 0;     // compile-time after unroll
        const int dstB = ((u + 1) & 1) ? BUFB : 0;
        char* slotC = reinterpret_cast<char*>(slots) + (size_t)(s & 3) * SLOTB;
        float dacc = 0.f;
        #pragma unroll
        for (int k = 0; k < 8; ++k) if (k < nr) {
            const uint2 g0 = *reinterpret_cast<const uint2*>(Xc + offB[k][0] + srcB);
            const uint2 g1 = *reinterpret_cast<const uint2*>(Xc + offB[k][1] + srcB);
            const uint2 g2 = *reinterpret_cast<const uint2*>(Xc + offB[k][2] + srcB);
            const f32x2 a01 = (unpk(g0.x) + unpk(g1.x)) + unpk(g2.x);
            const f32x2 a23 = (unpk(g0.y) + unpk(g1.y)) + unpk(g2.y);
            const f32x2 q01 = div3v(a01), q23 = div3v(a23);
            uint2 nv;
            nv.x = pkbf(q01.x, q01.y);
            nv.y = pkbf(q23.x, q23.y);
            *reinterpret_cast<uint2*>(Xc + r0b + ((k << 11) + dstB)) = nv;
            *reinterpret_cast<uint2*>(slotC + rowByte[k]) = nv;   // coalesced
            const f32x2 n01 = unpk(nv.x), n23 = unpk(nv.y);
            const f32x2 d01v = n01 - old01[k];
            const f32x2 d23v = n23 - old23[k];
            const u32 d01 = pkbf(d01v.x, d01v.y);
            const u32 d23 = pkbf(d23v.x, d23v.y);
            dacc += fabsf(bflo(d01));
            dacc += fabsf(bfhi(d01));
            dacc += fabsf(bflo(d23));
            dacc += fabsf(bfhi(d23));
            old01[k] = n01; old23[k] = n23;
        }
        #pragma unroll
        for (int off = 32; off > 0; off >>= 1) dacc += __shfl_down(dacc, off);
        if ((tid & 63) == 0) redL[u & 1][tid >> 6] = dacc;
        barrier_lds_only();                      // LDS wait only, no vm drain
        if (tid == 0) {
            const float dtot = ((redL[u & 1][0] + redL[u & 1][1])
                                + redL[u & 1][2]) + redL[u & 1][3];
            partials[((size_t)(s - 1) * BS + b) * NSLAB + sl] = dtot;
        }
    }

    // ---- fused findS: last workgroup to arrive scans partials --------------
    __threadfence();                              // release partials writes
    if (tid == 0) {
        const int old = atomicAdd(&ctrl[3], 1);   // device-scope
        lastFlag = (old == (int)gridDim.x - 1);
    }
    __syncthreads();
    if (!lastFlag) return;
    if (tid == 0) ctrl[3] = 0;                    // reset for next chunk
    if (tid < 64) {
        __threadfence();                          // acquire partials
        const int smax = sBeg + W - 1;
        const float tol_bf = bf2f(f2bf(1e-5f));
        int S = -1;
        for (int s = 1; s <= smax; ++s) {
            const float* p = partials + ((size_t)(s - 1) * BS + tid) * NSLAB;
            float t = 0.f;
            #pragma unroll
            for (int kk = 0; kk < NSLAB; ++kk) t += p[kk];
            const float lnorm = bf2f(f2bf(t / 261120.0f));
            if (__ballot(lnorm > tol_bf) == 0ULL) { S = s; break; }
        }
        if (S < 0 && smax == ITERS) S = ITERS;    // cap at MAX_ITERS
        if (tid == 0 && S > 0) { ctrl[0] = S; ctrl[2] = 1; }
    }
}

// ---------------------------------------------------------------------------
// copyFinal: slot S&3 -> finalX (ws). Both sides contiguous slab-major.
// Only used when slots live in d_out (convert would race them).
// ---------------------------------------------------------------------------
__global__ __launch_bounds__(256) void copyfinal_kernel(
        const int* __restrict__ ctrl, const u16* __restrict__ slots,
        u16* __restrict__ finalX) {
    const int S = ctrl[0];
    const uint4* src = reinterpret_cast<const uint4*>(slots + (size_t)(S & 3) * XB);
    uint4* dst = reinterpret_cast<uint4*>(finalX);
    const size_t n = XB / 8;
    for (size_t i = (size_t)blockIdx.x * 256 + threadIdx.x; i < n;
         i += (size_t)gridDim.x * 256)
        dst[i] = src[i];
}

// ---------------------------------------------------------------------------
// convert: d_out fp32 = [identity ; f32(bf16 X_S)] per batch.
// Source is slab-major: [wg = b*32+sl][row][16]. sel!=0 -> pick slot ctrl[0]&3.
// 32-B gathers, but source is fresh in L2/L3.
// ---------------------------------------------------------------------------
__global__ __launch_bounds__(64) void convert_kernel(
        const u16* __restrict__ base, const int* __restrict__ ctrl, int sel,
        float* __restrict__ out) {
    const int r = blockIdx.x;                    // 0..1021
    const int b = blockIdx.y;
    const int f0 = threadIdx.x << 3;             // 8 floats per thread
    float4 lo, hi;
    if (r < NTIPS) {
        lo.x = (r == f0 + 0) ? 1.f : 0.f;
        lo.y = (r == f0 + 1) ? 1.f : 0.f;
        lo.z = (r == f0 + 2) ? 1.f : 0.f;
        lo.w = (r == f0 + 3) ? 1.f : 0.f;
        hi.x = (r == f0 + 4) ? 1.f : 0.f;
        hi.y = (r == f0 + 5) ? 1.f : 0.f;
        hi.z = (r == f0 + 6) ? 1.f : 0.f;
        hi.w = (r == f0 + 7) ? 1.f : 0.f;
    } else {
        const u16* src = base + (sel ? (size_t)(ctrl[0] & 3) * XB : (size_t)0);
        const int sl = threadIdx.x >> 1;         // f0 >> 4
        const int fi = (threadIdx.x & 1) << 3;   // f0 & 15 (0 or 8)
        const u16* row = src + ((size_t)(b * NSLAB + sl) * DIM + (r - NTIPS)) * 16 + fi;
        const ushort4 a = *reinterpret_cast<const ushort4*>(row);
        const ushort4 c = *reinterpret_cast<const ushort4*>(row + 4);
        lo.x = bf2f(a.x); lo.y = bf2f(a.y); lo.z = bf2f(a.z); lo.w = bf2f(a.w);
        hi.x = bf2f(c.x); hi.y = bf2f(c.y); hi.z = bf2f(c.z); hi.w = bf2f(c.w);
    }
    float* drow = out + ((size_t)b * TOTAL + r) * NTIPS + f0;
    *reinterpret_cast<float4*>(drow)     = lo;
    *reinterpret_cast<float4*>(drow + 4) = hi;
}

extern "C" void kernel_launch(void* const* d_in, const int* in_sizes, int n_in,
                              void* d_out, int out_size, void* d_ws, size_t ws_size,
                              hipStream_t stream) {
    const int* edge = (const int*)d_in[1];       // (BS, TOTAL, 3) int32
    float* out = (float*)d_out;

    const size_t partB = NPART * sizeof(float);
    const bool ws_slots = ws_size >= 4 * SLOTB + partB + 256;

    u16* slots; float* partials;
    if (ws_slots) {                              // slots in ws: no copyfinal
        slots    = (u16*)d_ws;
        partials = (float*)((char*)d_ws + 4 * SLOTB);
    } else {                                     // slots in d_out, finalX in ws
        slots    = (u16*)d_out;
        partials = (float*)((char*)d_ws + SLOTB);
    }
    int* ctrl = (int*)((char*)partials + partB); // [S, unused, found, wgCount]

    hipMemsetAsync(ctrl, 0, 4 * sizeof(int), stream);

    // 12 chunks of width 4 + final width-2 chunk (steps 49..50).
    // sBeg = 4q-3 ≡ 1 (mod 4): slot s&3 never reused within a chunk.
    for (int q = 1; q <= 12; ++q)
        chunk_kernel<4><<<NWG, 256, 0, stream>>>(edge, partials, ctrl,
                                                 slots, q, 4 * q - 3);
    chunk_kernel<2><<<NWG, 256, 0, stream>>>(edge, partials, ctrl,
                                             slots, 13, 49);

    if (ws_slots) {
        convert_kernel<<<dim3(TOTAL, BS), 64, 0, stream>>>(slots, ctrl, 1, out);
    } else {
        u16* finalX = (u16*)d_ws;
        copyfinal_kernel<<<2048, 256, 0, stream>>>(ctrl, slots, finalX);
        convert_kernel<<<dim3(TOTAL, BS), 64, 0, stream>>>(finalX, ctrl, 0, out);
    }
}

// Round 3
// 317.297 us; speedup vs baseline: 5.3117x; 3.7526x over previous
//
#include <hip/hip_runtime.h>

#define NTIPS 512
#define DIM   510                     // internal nodes = ntips - 2
#define TOTAL 1022
#define BS    64
#define ITERS 50
#define SLABF 16                      // features per workgroup slab
#define NSLAB 32
#define NWG   (BS * NSLAB)            // 2048 workgroups
#define NPART ((size_t)ITERS * BS * NSLAB)

#define ROWEL 16                      // u16 elems per row-slab (32 B)
#define XSEC   (DIM * ROWEL)          // evolving X section
#define ONEOFF XSEC                   // 16 one-hot const rows
#define ZROW   (XSEC + 16 * ROWEL)    // all-zero const row
#define BSTRIDE (XSEC + 17 * ROWEL)   // u16 per LDS buffer
#define BUFB   (BSTRIDE * 2)          // bytes per LDS buffer = 16864

#define XB ((size_t)BS * DIM * NTIPS) // u16 elems per snapshot slot
#define SLOTB (XB * 2)                // bytes per snapshot slot (33.4 MB)
#define WGB  (DIM * ROWEL * 2)        // bytes per WG region in a slot = 16320

typedef unsigned short u16;
typedef unsigned int   u32;
typedef float f32x2 __attribute__((ext_vector_type(2)));

// bf16 RNE helpers
__device__ __forceinline__ u16 f2bf(float x) {
    u32 u = __float_as_uint(x);
    return (u16)((u + 0x7FFFu + ((u >> 16) & 1u)) >> 16);
}
__device__ __forceinline__ float bf2f(u16 h) { return __uint_as_float(((u32)h) << 16); }
__device__ __forceinline__ float bflo(u32 p) { return __uint_as_float(p << 16); }
__device__ __forceinline__ float bfhi(u32 p) { return __uint_as_float(p & 0xFFFF0000u); }
__device__ __forceinline__ f32x2 unpk(u32 p) {
    f32x2 r; r.x = bflo(p); r.y = bfhi(p); return r;   // (lo elem, hi elem)
}

#if defined(__has_builtin)
#  if __has_builtin(__builtin_amdgcn_cvt_pk_bf16_f32)
#    define HAVE_PKBF 1
#  endif
#endif
#ifdef HAVE_PKBF
typedef __bf16 bf16x2 __attribute__((ext_vector_type(2)));
__device__ __forceinline__ u32 pkbf(float a, float b) {   // lo=a, hi=b, RNE
    bf16x2 r = __builtin_amdgcn_cvt_pk_bf16_f32(a, b);
    return __builtin_bit_cast(u32, r);
}
#else
__device__ __forceinline__ u32 pkbf(float a, float b) {
    return (u32)f2bf(a) | ((u32)f2bf(b) << 16);
}
#endif

// correctly-rounded f32 division by 3 (Markstein mul+2fma) — R2-validated
__device__ __forceinline__ f32x2 div3v(f32x2 x) {
    const float C = 0x1.555556p-2f;               // RN(1/3)
    f32x2 q0, r, q;
    q0.x = x.x * C;             q0.y = x.y * C;
    r.x = fmaf(-3.f, q0.x, x.x); r.y = fmaf(-3.f, q0.y, x.y);
    q.x = fmaf(r.x, C, q0.x);    q.y = fmaf(r.y, C, q0.y);
    return q;
}

// LDS-only barrier: waits LDS ops, does NOT drain vmcnt (snapshot stores
// stay in flight across steps). m201/HK pattern + rule-#18 sched guards.
__device__ __forceinline__ void barrier_lds_only() {
    __builtin_amdgcn_sched_barrier(0);
    asm volatile("s_waitcnt lgkmcnt(0)" ::: "memory");
    __builtin_amdgcn_s_barrier();
    __builtin_amdgcn_sched_barrier(0);
}

// register-resident gather offsets (BYTE units, LDS-buffer-relative)
__device__ __forceinline__ void make_offsets(const int* __restrict__ edge,
        int b, int sl, int rg, int lbyte, int nr, u32 offB[8][3]) {
    #pragma unroll
    for (int k = 0; k < 8; ++k) if (k < nr) {
        const int i = rg + 64 * k;
        const int* ep = edge + ((size_t)b * TOTAL + NTIPS + i) * 3;
        #pragma unroll
        for (int t = 0; t < 3; ++t) {
            const int e = ep[t];
            u32 off;
            if (e >= NTIPS)          off = (u32)((e - NTIPS) * ROWEL);
            else if ((e >> 4) == sl) off = (u32)(ONEOFF + (e & 15) * ROWEL);
            else                     off = (u32)ZROW;
            offB[k][t] = off * 2u + (u32)lbyte;
        }
    }
}

__device__ __forceinline__ void init_const_rows(u16* X, int tid) {
    for (int j = tid; j < 17 * ROWEL; j += 256) {
        const int row = j >> 4, col = j & 15;
        const u16 v = (row == col) ? (u16)0x3F80 : (u16)0;  // row 16 = zeros
        X[ONEOFF + j] = v;
        X[BSTRIDE + ONEOFF + j] = v;
    }
}

// ---------------------------------------------------------------------------
// chunk q: W steps (sBeg..sBeg+W-1), sBeg ≡ 1 (mod MASK+1).
// Snapshots EVERY step s into slot s&MASK, slab-major (coalesced 512 B/wave).
// NO device fences / atomics in here — R1/R2's per-WG __threadfence caused
// 2048 L2-writeback storms per chunk (the 400 GB/s wall). findS is a
// separate dispatch; the kernel boundary provides visibility once.
// ---------------------------------------------------------------------------
template<int W, int MASK>
__global__ __launch_bounds__(256, 4) void chunk_kernel(
        const int* __restrict__ edge, float* __restrict__ partials,
        const int* __restrict__ ctrl, u16* __restrict__ slots, int q, int sBeg) {
    if (q >= 2 && ctrl[2] != 0) return;          // converged: skip

    __shared__ u16 X[2 * BSTRIDE];
    __shared__ float redL[2][4];

    const int wg = blockIdx.x, b = wg >> 5, sl = wg & 31;
    const int tid = threadIdx.x, rg = tid >> 2;
    const int lbyte = (tid & 3) << 3;            // byte offset in row (8 B)
    const int nr = (rg < 62) ? 8 : 7;
    char* Xc = reinterpret_cast<char*>(X);
    const u32 r0b = (u32)(rg * 32 + lbyte);      // own-row LDS byte base

    u32 offB[8][3];
    make_offsets(edge, b, sl, rg, lbyte, nr, offB);

    // slab-major global byte offsets of own rows within one snapshot slot
    u32 rowByte[8];
    #pragma unroll
    for (int k = 0; k < 8; ++k)
        rowByte[k] = (u32)wg * (u32)WGB + (u32)((rg + 64 * k) * 32) + (u32)lbyte;

    if (q == 1) {
        for (int j = tid; j < XSEC / 2; j += 256)
            reinterpret_cast<u32*>(X)[j] = 0x3B003B00u;   // X0 = bf16(1/512)
    } else {
        const char* src0 = reinterpret_cast<const char*>(slots)
                         + (size_t)((sBeg - 1) & MASK) * SLOTB;
        #pragma unroll
        for (int k = 0; k < 8; ++k) if (k < nr)
            *reinterpret_cast<uint2*>(Xc + r0b + (k << 11)) =
                *reinterpret_cast<const uint2*>(src0 + rowByte[k]);
    }
    init_const_rows(X, tid);

    // old-row values in registers (own rows, written by self — no barrier)
    f32x2 old01[8], old23[8];
    #pragma unroll
    for (int k = 0; k < 8; ++k) if (k < nr) {
        const uint2 ov = *reinterpret_cast<const uint2*>(Xc + r0b + (k << 11));
        old01[k] = unpk(ov.x); old23[k] = unpk(ov.y);
    }
    __syncthreads();

    #pragma unroll
    for (int u = 0; u < W; ++u) {
        const int s = sBeg + u;
        const int srcB = (u & 1) ? BUFB : 0;     // compile-time after unroll
        const int dstB = ((u + 1) & 1) ? BUFB : 0;
        char* slotC = reinterpret_cast<char*>(slots) + (size_t)(s & MASK) * SLOTB;
        float dacc = 0.f;
        #pragma unroll
        for (int k = 0; k < 8; ++k) if (k < nr) {
            const uint2 g0 = *reinterpret_cast<const uint2*>(Xc + offB[k][0] + srcB);
            const uint2 g1 = *reinterpret_cast<const uint2*>(Xc + offB[k][1] + srcB);
            const uint2 g2 = *reinterpret_cast<const uint2*>(Xc + offB[k][2] + srcB);
            const f32x2 a01 = (unpk(g0.x) + unpk(g1.x)) + unpk(g2.x);
            const f32x2 a23 = (unpk(g0.y) + unpk(g1.y)) + unpk(g2.y);
            const f32x2 q01 = div3v(a01), q23 = div3v(a23);
            uint2 nv;
            nv.x = pkbf(q01.x, q01.y);
            nv.y = pkbf(q23.x, q23.y);
            *reinterpret_cast<uint2*>(Xc + r0b + ((k << 11) + dstB)) = nv;
            *reinterpret_cast<uint2*>(slotC + rowByte[k]) = nv;   // coalesced
            const f32x2 n01 = unpk(nv.x), n23 = unpk(nv.y);
            const f32x2 d01v = n01 - old01[k];
            const f32x2 d23v = n23 - old23[k];
            const u32 d01 = pkbf(d01v.x, d01v.y);
            const u32 d23 = pkbf(d23v.x, d23v.y);
            dacc += fabsf(bflo(d01));
            dacc += fabsf(bfhi(d01));
            dacc += fabsf(bflo(d23));
            dacc += fabsf(bfhi(d23));
            old01[k] = n01; old23[k] = n23;
        }
        #pragma unroll
        for (int off = 32; off > 0; off >>= 1) dacc += __shfl_down(dacc, off);
        if ((tid & 63) == 0) redL[u & 1][tid >> 6] = dacc;
        barrier_lds_only();                      // LDS wait only, no vm drain
        if (tid == 0) {
            const float dtot = ((redL[u & 1][0] + redL[u & 1][1])
                                + redL[u & 1][2]) + redL[u & 1][3];
            partials[((size_t)(s - 1) * BS + b) * NSLAB + sl] = dtot;
        }
    }
}

// ---------------------------------------------------------------------------
// findS (separate dispatch — visibility via kernel boundary, no fences).
// Scan s=1..smax with the validated decision procedure.
// ---------------------------------------------------------------------------
__global__ void findS_kernel(const float* __restrict__ partials,
                             int* __restrict__ ctrl, int smax) {
    if (ctrl[2] != 0) return;
    const int lane = threadIdx.x;                // 64 lanes = trees
    const float tol_bf = bf2f(f2bf(1e-5f));
    int S = -1;
    for (int s = 1; s <= smax; ++s) {
        const float* p = partials + ((size_t)(s - 1) * BS + lane) * NSLAB;
        float t = 0.f;
        #pragma unroll
        for (int k = 0; k < NSLAB; ++k) t += p[k];
        const float lnorm = bf2f(f2bf(t / 261120.0f));
        if (__ballot(lnorm > tol_bf) == 0ULL) { S = s; break; }
    }
    if (S < 0 && smax == ITERS) S = ITERS;       // cap at MAX_ITERS
    if (lane == 0 && S > 0) { ctrl[0] = S; ctrl[2] = 1; }
}

// ---------------------------------------------------------------------------
// copyFinal: slot S&3 -> finalX (ws). Used only when slots live in d_out.
// ---------------------------------------------------------------------------
__global__ __launch_bounds__(256) void copyfinal_kernel(
        const int* __restrict__ ctrl, const u16* __restrict__ slots,
        u16* __restrict__ finalX) {
    const int S = ctrl[0];
    const uint4* src = reinterpret_cast<const uint4*>(slots + (size_t)(S & 3) * XB);
    uint4* dst = reinterpret_cast<uint4*>(finalX);
    const size_t n = XB / 8;
    for (size_t i = (size_t)blockIdx.x * 256 + threadIdx.x; i < n;
         i += (size_t)gridDim.x * 256)
        dst[i] = src[i];
}

// ---------------------------------------------------------------------------
// convert: d_out fp32 = [identity ; f32(bf16 X_S)] per batch.
// Source slab-major [wg][row][16]. mask>=0 -> slot ctrl[0]&mask, else direct.
// ---------------------------------------------------------------------------
__global__ __launch_bounds__(64) void convert_kernel(
        const u16* __restrict__ base, const int* __restrict__ ctrl, int mask,
        float* __restrict__ out) {
    const int r = blockIdx.x;                    // 0..1021
    const int b = blockIdx.y;
    const int f0 = threadIdx.x << 3;             // 8 floats per thread
    float4 lo, hi;
    if (r < NTIPS) {
        lo.x = (r == f0 + 0) ? 1.f : 0.f;
        lo.y = (r == f0 + 1) ? 1.f : 0.f;
        lo.z = (r == f0 + 2) ? 1.f : 0.f;
        lo.w = (r == f0 + 3) ? 1.f : 0.f;
        hi.x = (r == f0 + 4) ? 1.f : 0.f;
        hi.y = (r == f0 + 5) ? 1.f : 0.f;
        hi.z = (r == f0 + 6) ? 1.f : 0.f;
        hi.w = (r == f0 + 7) ? 1.f : 0.f;
    } else {
        const u16* src = base + (mask >= 0 ? (size_t)(ctrl[0] & mask) * XB
                                           : (size_t)0);
        const int sl = threadIdx.x >> 1;         // f0 >> 4
        const int fi = (threadIdx.x & 1) << 3;   // f0 & 15 (0 or 8)
        const u16* row = src + ((size_t)(b * NSLAB + sl) * DIM + (r - NTIPS)) * 16 + fi;
        const ushort4 a = *reinterpret_cast<const ushort4*>(row);
        const ushort4 c = *reinterpret_cast<const ushort4*>(row + 4);
        lo.x = bf2f(a.x); lo.y = bf2f(a.y); lo.z = bf2f(a.z); lo.w = bf2f(a.w);
        hi.x = bf2f(c.x); hi.y = bf2f(c.y); hi.z = bf2f(c.z); hi.w = bf2f(c.w);
    }
    float* drow = out + ((size_t)b * TOTAL + r) * NTIPS + f0;
    *reinterpret_cast<float4*>(drow)     = lo;
    *reinterpret_cast<float4*>(drow + 4) = hi;
}

extern "C" void kernel_launch(void* const* d_in, const int* in_sizes, int n_in,
                              void* d_out, int out_size, void* d_ws, size_t ws_size,
                              hipStream_t stream) {
    const int* edge = (const int*)d_in[1];       // (BS, TOTAL, 3) int32
    float* out = (float*)d_out;
    const size_t partB = NPART * sizeof(float);

    if (ws_size >= 8 * SLOTB + partB + 256) {
        // -------- 8-slot schedule in ws: 6×W8 + W2, fewest launches --------
        u16*   slots    = (u16*)d_ws;
        float* partials = (float*)((char*)d_ws + 8 * SLOTB);
        int*   ctrl     = (int*)((char*)partials + partB);
        hipMemsetAsync(ctrl, 0, 4 * sizeof(int), stream);
        for (int q = 1; q <= 6; ++q) {
            chunk_kernel<8, 7><<<NWG, 256, 0, stream>>>(edge, partials, ctrl,
                                                        slots, q, 8 * q - 7);
            findS_kernel<<<1, 64, 0, stream>>>(partials, ctrl, 8 * q);
        }
        chunk_kernel<2, 7><<<NWG, 256, 0, stream>>>(edge, partials, ctrl,
                                                    slots, 7, 49);
        findS_kernel<<<1, 64, 0, stream>>>(partials, ctrl, 50);
        convert_kernel<<<dim3(TOTAL, BS), 64, 0, stream>>>(slots, ctrl, 7, out);
    } else if (ws_size >= 4 * SLOTB + partB + 256) {
        // -------- 4-slot schedule in ws: 12×W4 + W2 ------------------------
        u16*   slots    = (u16*)d_ws;
        float* partials = (float*)((char*)d_ws + 4 * SLOTB);
        int*   ctrl     = (int*)((char*)partials + partB);
        hipMemsetAsync(ctrl, 0, 4 * sizeof(int), stream);
        for (int q = 1; q <= 12; ++q) {
            chunk_kernel<4, 3><<<NWG, 256, 0, stream>>>(edge, partials, ctrl,
                                                        slots, q, 4 * q - 3);
            findS_kernel<<<1, 64, 0, stream>>>(partials, ctrl, 4 * q);
        }
        chunk_kernel<2, 3><<<NWG, 256, 0, stream>>>(edge, partials, ctrl,
                                                    slots, 13, 49);
        findS_kernel<<<1, 64, 0, stream>>>(partials, ctrl, 50);
        convert_kernel<<<dim3(TOTAL, BS), 64, 0, stream>>>(slots, ctrl, 3, out);
    } else {
        // -------- fallback: 4 slots in d_out, finalX in ws -----------------
        u16*   slots    = (u16*)d_out;
        u16*   finalX   = (u16*)d_ws;
        float* partials = (float*)((char*)d_ws + SLOTB);
        int*   ctrl     = (int*)((char*)partials + partB);
        hipMemsetAsync(ctrl, 0, 4 * sizeof(int), stream);
        for (int q = 1; q <= 12; ++q) {
            chunk_kernel<4, 3><<<NWG, 256, 0, stream>>>(edge, partials, ctrl,
                                                        slots, q, 4 * q - 3);
            findS_kernel<<<1, 64, 0, stream>>>(partials, ctrl, 4 * q);
        }
        chunk_kernel<2, 3><<<NWG, 256, 0, stream>>>(edge, partials, ctrl,
                                                    slots, 13, 49);
        findS_kernel<<<1, 64, 0, stream>>>(partials, ctrl, 50);
        copyfinal_kernel<<<2048, 256, 0, stream>>>(ctrl, slots, finalX);
        convert_kernel<<<dim3(TOTAL, BS), 64, 0, stream>>>(finalX, ctrl, -1, out);
    }
}